// Round 1
// baseline (1107.828 us; speedup 1.0000x reference)
//
#include <hip/hip_runtime.h>
#include <stdint.h>

#define NTOK 8192
#define DDIM 1024
#define FDIM 2752
#define NEXP 8
#define DF2  5504   // 2F
#define NSLOT 16384 // NTOK * TOPK

typedef __attribute__((ext_vector_type(8))) short bf16x8;
typedef __attribute__((ext_vector_type(4))) float f32x4;
typedef __attribute__((ext_vector_type(4))) unsigned short u16x4;
typedef __attribute__((ext_vector_type(8))) unsigned short u16x8;

// ---- workspace layout (bytes) ----
constexpr size_t XB_OFF   = 0;                                   // x bf16 [NTOK][DDIM]
constexpr size_t XB_SZ    = (size_t)NTOK * DDIM * 2;
constexpr size_t W13T_OFF = XB_OFF + XB_SZ;                      // W13^T bf16 [E][2F][D]
constexpr size_t W13T_SZ  = (size_t)NEXP * DF2 * DDIM * 2;
constexpr size_t W2T_OFF  = W13T_OFF + W13T_SZ;                  // W2^T bf16 [E][D][F]
constexpr size_t W2T_SZ   = (size_t)NEXP * DDIM * FDIM * 2;
constexpr size_t H_OFF    = W2T_OFF + W2T_SZ;                    // h bf16 [NSLOT][F]
constexpr size_t H_SZ     = (size_t)NSLOT * FDIM * 2;
constexpr size_t ST_OFF   = H_OFF + H_SZ;                        // slot_token i32
constexpr size_t SW_OFF   = ST_OFF + (size_t)NSLOT * 4;          // slot_weight f32
constexpr size_t TTI_OFF  = SW_OFF + (size_t)NSLOT * 4;          // per-token top2 idx (int2)
constexpr size_t TTW_OFF  = TTI_OFF + (size_t)NTOK * 8;          // per-token top2 w (float2)
constexpr size_t META_OFF = TTW_OFF + (size_t)NTOK * 8;          // cnt[8], cnt2[8], off[8]
// total ~243 MB

__device__ __forceinline__ unsigned short f2bf(float f) {
  unsigned u = __float_as_uint(f);
  u += 0x7FFFu + ((u >> 16) & 1u);     // RNE
  return (unsigned short)(u >> 16);
}

__device__ __forceinline__ void gl_lds16(const void* g, void* l) {
  __builtin_amdgcn_global_load_lds(
      (const __attribute__((address_space(1))) unsigned int*)g,
      (__attribute__((address_space(3))) unsigned int*)l, 16, 0, 0);
}

// ---------------- convert x -> bf16 ----------------
__global__ void cvt_x_k(const float* __restrict__ x, unsigned short* __restrict__ xb) {
  int i = blockIdx.x * 256 + threadIdx.x;            // over NTOK*DDIM/4
  float4 v = ((const float4*)x)[i];
  u16x4 o;
  o[0] = f2bf(v.x); o[1] = f2bf(v.y); o[2] = f2bf(v.z); o[3] = f2bf(v.w);
  ((u16x4*)xb)[i] = o;
}

// ---------------- transpose + convert weights ----------------
// src: [R][C] fp32 per expert, dst: [C][R] bf16 per expert. grid (C/64, R/64, E)
__global__ void tcvt_k(const float* __restrict__ src, unsigned short* __restrict__ dst,
                       int R, int C) {
  __shared__ unsigned short tile[64][65];
  long base = (long)blockIdx.z * R * C;
  src += base; dst += base;
  int r0 = blockIdx.y * 64, c0 = blockIdx.x * 64;
  int t = threadIdx.x;
  int rr = t >> 4, cc = (t & 15) * 4;
  for (int i = 0; i < 4; ++i) {
    float4 v = *(const float4*)&src[(long)(r0 + rr + i * 16) * C + c0 + cc];
    tile[rr + i * 16][cc + 0] = f2bf(v.x);
    tile[rr + i * 16][cc + 1] = f2bf(v.y);
    tile[rr + i * 16][cc + 2] = f2bf(v.z);
    tile[rr + i * 16][cc + 3] = f2bf(v.w);
  }
  __syncthreads();
  int dr = t >> 2, sg = (t & 3) * 16;
  u16x8 o0, o1;
  for (int i = 0; i < 8; ++i) { o0[i] = tile[sg + i][dr]; o1[i] = tile[sg + 8 + i][dr]; }
  unsigned short* dp = &dst[(long)(c0 + dr) * R + r0 + sg];
  *(u16x8*)dp = o0;
  *(u16x8*)(dp + 8) = o1;
}

// ---------------- router: logits, softmax, top2 ----------------
__global__ void router_k(const float* __restrict__ x, const float* __restrict__ Wr,
                         int* __restrict__ meta, int2* __restrict__ tt_i,
                         float2* __restrict__ tt_w) {
  int lane = threadIdx.x & 63;
  int tok = blockIdx.x * 4 + (threadIdx.x >> 6);
  float acc[8];
#pragma unroll
  for (int e = 0; e < 8; ++e) acc[e] = 0.f;
  const float4* xr = (const float4*)(x + (long)tok * DDIM);
#pragma unroll
  for (int it = 0; it < 4; ++it) {
    float4 v = xr[it * 64 + lane];
    int d = (it * 64 + lane) * 4;
    float xv[4] = {v.x, v.y, v.z, v.w};
#pragma unroll
    for (int j = 0; j < 4; ++j) {
      const float4* wr = (const float4*)(Wr + (long)(d + j) * NEXP);
      float4 wa = wr[0], wb = wr[1];
      acc[0] += xv[j] * wa.x; acc[1] += xv[j] * wa.y;
      acc[2] += xv[j] * wa.z; acc[3] += xv[j] * wa.w;
      acc[4] += xv[j] * wb.x; acc[5] += xv[j] * wb.y;
      acc[6] += xv[j] * wb.z; acc[7] += xv[j] * wb.w;
    }
  }
#pragma unroll
  for (int e = 0; e < 8; ++e)
    for (int off = 32; off; off >>= 1) acc[e] += __shfl_xor(acc[e], off, 64);
  if (lane == 0) {
    float m = acc[0];
    for (int e = 1; e < 8; ++e) m = fmaxf(m, acc[e]);
    float p[8];
    for (int e = 0; e < 8; ++e) p[e] = __expf(acc[e] - m);
    int e0 = 0;
    for (int e = 1; e < 8; ++e) if (p[e] > p[e0]) e0 = e;      // first max (jax tie rule)
    int e1 = -1;
    for (int e = 0; e < 8; ++e) { if (e == e0) continue; if (e1 < 0 || p[e] > p[e1]) e1 = e; }
    float s = p[e0] + p[e1];
    atomicAdd(&meta[e0], 1);
    atomicAdd(&meta[e1], 1);
    tt_i[tok] = make_int2(e0, e1);
    tt_w[tok] = make_float2(p[e0] / s, p[e1] / s);
  }
}

// ---------------- prefix offsets ----------------
__global__ void offsets_k(int* meta) {
  int run = 0;
  for (int e = 0; e < NEXP; ++e) { meta[16 + e] = run; run += meta[e]; }
}

// ---------------- scatter tokens to expert slots ----------------
__global__ void scatter_k(const int2* __restrict__ tt_i, const float2* __restrict__ tt_w,
                          int* __restrict__ meta, int* __restrict__ slot_tok,
                          float* __restrict__ slot_w) {
  int n = blockIdx.x * 256 + threadIdx.x;
  int2 ei = tt_i[n];
  float2 wv = tt_w[n];
  int p0 = atomicAdd(&meta[8 + ei.x], 1);
  int s0 = meta[16 + ei.x] + p0;
  slot_tok[s0] = n; slot_w[s0] = wv.x;
  int p1 = atomicAdd(&meta[8 + ei.y], 1);
  int s1 = meta[16 + ei.y] + p1;
  slot_tok[s1] = n; slot_w[s1] = wv.y;
}

// ---------------- GEMM1 + SwiGLU: h = silu(X@W1) * (X@W3) ----------------
// grid (FDIM/64, NTOK/128, E), block 256. Tile: 128 slots x (64 gate + 64 up).
__global__ __launch_bounds__(256) void gemm1_k(
    const unsigned short* __restrict__ xb, const unsigned short* __restrict__ w13t,
    const int* __restrict__ meta, const int* __restrict__ slot_tok,
    unsigned short* __restrict__ h) {
  int e = blockIdx.z;
  int n_e = meta[e];
  int m0 = blockIdx.y * 128;
  if (m0 >= n_e) return;
  int base = meta[16 + e];
  int c0 = blockIdx.x * 64;
  const unsigned short* wB = w13t + (long)e * DF2 * DDIM;

  __shared__ unsigned short Al[128 * 32];
  __shared__ unsigned short B1l[64 * 32];
  __shared__ unsigned short B2l[64 * 32];

  int t = threadIdx.x;
  int lane = t & 63, w = t >> 6;
  int wm = w & 1, wn = w >> 1;
  int ar0 = t >> 2, ac = (t & 3) * 8;

  int tokA0 = slot_tok[base + min(m0 + ar0, n_e - 1)];
  int tokA1 = slot_tok[base + min(m0 + 64 + ar0, n_e - 1)];
  const unsigned short* gA0 = xb + (long)tokA0 * DDIM + ac;
  const unsigned short* gA1 = xb + (long)tokA1 * DDIM + ac;
  const unsigned short* gB1 = wB + (long)(c0 + ar0) * DDIM + ac;
  const unsigned short* gB2 = gB1 + (long)FDIM * DDIM;

  unsigned short* lA0 = &Al[t * 8];
  unsigned short* lA1 = &Al[(t + 256) * 8];
  unsigned short* lB1 = &B1l[t * 8];
  unsigned short* lB2 = &B2l[t * 8];

  f32x4 accg[4][2], accu[4][2];
#pragma unroll
  for (int mi = 0; mi < 4; ++mi)
#pragma unroll
    for (int ni = 0; ni < 2; ++ni) {
      accg[mi][ni] = (f32x4){0.f, 0.f, 0.f, 0.f};
      accu[mi][ni] = (f32x4){0.f, 0.f, 0.f, 0.f};
    }

  for (int k0 = 0; k0 < DDIM; k0 += 32) {
    gl_lds16(gA0 + k0, lA0);
    gl_lds16(gA1 + k0, lA1);
    gl_lds16(gB1 + k0, lB1);
    gl_lds16(gB2 + k0, lB2);
    __syncthreads();
    int q8 = (lane >> 4) * 8;
    bf16x8 a[4], b1[2], b2[2];
#pragma unroll
    for (int mi = 0; mi < 4; ++mi)
      a[mi] = *(const bf16x8*)&Al[(wm * 64 + mi * 16 + (lane & 15)) * 32 + q8];
#pragma unroll
    for (int ni = 0; ni < 2; ++ni) {
      b1[ni] = *(const bf16x8*)&B1l[(wn * 32 + ni * 16 + (lane & 15)) * 32 + q8];
      b2[ni] = *(const bf16x8*)&B2l[(wn * 32 + ni * 16 + (lane & 15)) * 32 + q8];
    }
#pragma unroll
    for (int mi = 0; mi < 4; ++mi)
#pragma unroll
      for (int ni = 0; ni < 2; ++ni) {
        accg[mi][ni] = __builtin_amdgcn_mfma_f32_16x16x32_bf16(a[mi], b1[ni], accg[mi][ni], 0, 0, 0);
        accu[mi][ni] = __builtin_amdgcn_mfma_f32_16x16x32_bf16(a[mi], b2[ni], accu[mi][ni], 0, 0, 0);
      }
    __syncthreads();
  }
  // epilogue: SwiGLU -> h (bf16). C/D: col=lane&15, row=quad*4+reg
  int quad = lane >> 4;
  int col0 = c0 + wn * 32 + (lane & 15);
#pragma unroll
  for (int mi = 0; mi < 4; ++mi)
#pragma unroll
    for (int r = 0; r < 4; ++r) {
      int m = m0 + wm * 64 + mi * 16 + quad * 4 + r;
      if (m < n_e) {
        unsigned short* hp = &h[(long)(base + m) * FDIM + col0];
#pragma unroll
        for (int ni = 0; ni < 2; ++ni) {
          float g = accg[mi][ni][r], u = accu[mi][ni][r];
          float hv = (g / (1.f + __expf(-g))) * u;
          hp[ni * 16] = f2bf(hv);
        }
      }
    }
}

// ---------------- GEMM2 + weighted scatter-add: out += w * (h @ W2) ----------------
// grid (DDIM/128, NTOK/128, E), block 256. Tile 128x128.
__global__ __launch_bounds__(256) void gemm2_k(
    const unsigned short* __restrict__ h, const unsigned short* __restrict__ w2t,
    const int* __restrict__ meta, const int* __restrict__ slot_tok,
    const float* __restrict__ slot_w, float* __restrict__ out) {
  int e = blockIdx.z;
  int n_e = meta[e];
  int m0 = blockIdx.y * 128;
  if (m0 >= n_e) return;
  int base = meta[16 + e];
  int n0 = blockIdx.x * 128;
  const unsigned short* wB = w2t + (long)e * DDIM * FDIM;

  __shared__ unsigned short Al[128 * 32];
  __shared__ unsigned short Bl[128 * 32];

  int t = threadIdx.x;
  int lane = t & 63, w = t >> 6;
  int wm = w & 1, wn = w >> 1;
  int ar0 = t >> 2, ac = (t & 3) * 8;

  int rA0 = base + min(m0 + ar0, n_e - 1);
  int rA1 = base + min(m0 + 64 + ar0, n_e - 1);
  const unsigned short* gA0 = h + (long)rA0 * FDIM + ac;
  const unsigned short* gA1 = h + (long)rA1 * FDIM + ac;
  const unsigned short* gB0 = wB + (long)(n0 + ar0) * FDIM + ac;
  const unsigned short* gB1 = gB0 + (long)64 * FDIM;

  unsigned short* lA0 = &Al[t * 8];
  unsigned short* lA1 = &Al[(t + 256) * 8];
  unsigned short* lB0 = &Bl[t * 8];
  unsigned short* lB1 = &Bl[(t + 256) * 8];

  f32x4 acc[4][4];
#pragma unroll
  for (int mi = 0; mi < 4; ++mi)
#pragma unroll
    for (int ni = 0; ni < 4; ++ni) acc[mi][ni] = (f32x4){0.f, 0.f, 0.f, 0.f};

  for (int k0 = 0; k0 < FDIM; k0 += 32) {
    gl_lds16(gA0 + k0, lA0);
    gl_lds16(gA1 + k0, lA1);
    gl_lds16(gB0 + k0, lB0);
    gl_lds16(gB1 + k0, lB1);
    __syncthreads();
    int q8 = (lane >> 4) * 8;
    bf16x8 a[4], b[4];
#pragma unroll
    for (int mi = 0; mi < 4; ++mi)
      a[mi] = *(const bf16x8*)&Al[(wm * 64 + mi * 16 + (lane & 15)) * 32 + q8];
#pragma unroll
    for (int ni = 0; ni < 4; ++ni)
      b[ni] = *(const bf16x8*)&Bl[(wn * 64 + ni * 16 + (lane & 15)) * 32 + q8];
#pragma unroll
    for (int mi = 0; mi < 4; ++mi)
#pragma unroll
      for (int ni = 0; ni < 4; ++ni)
        acc[mi][ni] = __builtin_amdgcn_mfma_f32_16x16x32_bf16(a[mi], b[ni], acc[mi][ni], 0, 0, 0);
    __syncthreads();
  }
  int quad = lane >> 4;
#pragma unroll
  for (int mi = 0; mi < 4; ++mi)
#pragma unroll
    for (int r = 0; r < 4; ++r) {
      int m = m0 + wm * 64 + mi * 16 + quad * 4 + r;
      if (m < n_e) {
        int tok = slot_tok[base + m];
        float wgt = slot_w[base + m];
        float* op = out + (long)tok * DDIM + n0 + wn * 64 + (lane & 15);
#pragma unroll
        for (int ni = 0; ni < 4; ++ni) atomicAdd(op + ni * 16, wgt * acc[mi][ni][r]);
      }
    }
}

extern "C" void kernel_launch(void* const* d_in, const int* in_sizes, int n_in,
                              void* d_out, int out_size, void* d_ws, size_t ws_size,
                              hipStream_t stream) {
  const float* x   = (const float*)d_in[0];
  const float* W13 = (const float*)d_in[1];
  const float* W2  = (const float*)d_in[2];
  const float* Wr  = (const float*)d_in[3];
  float* out = (float*)d_out;
  char* ws = (char*)d_ws;

  unsigned short* xb   = (unsigned short*)(ws + XB_OFF);
  unsigned short* w13t = (unsigned short*)(ws + W13T_OFF);
  unsigned short* w2t  = (unsigned short*)(ws + W2T_OFF);
  unsigned short* hbuf = (unsigned short*)(ws + H_OFF);
  int*    slot_tok = (int*)(ws + ST_OFF);
  float*  slot_w   = (float*)(ws + SW_OFF);
  int2*   tt_i     = (int2*)(ws + TTI_OFF);
  float2* tt_w     = (float2*)(ws + TTW_OFF);
  int*    meta     = (int*)(ws + META_OFF);

  hipMemsetAsync(d_out, 0, (size_t)NTOK * DDIM * sizeof(float), stream);
  hipMemsetAsync(meta, 0, 128, stream);

  cvt_x_k<<<NTOK * DDIM / 4 / 256, 256, 0, stream>>>(x, xb);
  tcvt_k<<<dim3(DF2 / 64, DDIM / 64, NEXP), 256, 0, stream>>>(W13, w13t, DDIM, DF2);
  tcvt_k<<<dim3(DDIM / 64, FDIM / 64, NEXP), 256, 0, stream>>>(W2, w2t, FDIM, DDIM);
  router_k<<<NTOK / 4, 256, 0, stream>>>(x, Wr, meta, tt_i, tt_w);
  offsets_k<<<1, 1, 0, stream>>>(meta);
  scatter_k<<<NTOK / 256, 256, 0, stream>>>(tt_i, tt_w, meta, slot_tok, slot_w);
  gemm1_k<<<dim3(FDIM / 64, NTOK / 128, NEXP), 256, 0, stream>>>(xb, w13t, meta, slot_tok, hbuf);
  gemm2_k<<<dim3(DDIM / 128, NTOK / 128, NEXP), 256, 0, stream>>>(hbuf, w2t, meta, slot_tok, slot_w, out);
}